// Round 1
// baseline (630.382 us; speedup 1.0000x reference)
//
#include <hip/hip_runtime.h>
#include <hip/hip_fp16.h>

// Problem: B=512, IN_F=512, OUT_F=512, NOISE=128, OUT_DIM = 512*512+512
// out[b,o] = sum_{i,n} x[b,i]*noise[b,n]*hW[i*512+o, n]          (main, branch 0)
//          + sum_{i,n} px[b,i]*noise[b,n]*pW[i*512+o, n]         (main, branch 1)
//          + sum_i x[b,i]*hb[i*512+o] + sum_i px[b,i]*pb[i*512+o] (epilogue E1)
//          + sum_n noise[b,n]*(hW[(262144+o),n]+pW[(262144+o),n]) (epilogue E2)
//          + hb[262144+o] + pb[262144+o]                          (epilogue tail)
// PRIOR_SCALE = 1.0 (folded).

#define MAIN_D (512*512)   // 262144

typedef _Float16 half8 __attribute__((ext_vector_type(8)));
typedef float floatx4 __attribute__((ext_vector_type(4)));

static __device__ __forceinline__ unsigned h2u(__half2 h) {
    union { __half2 h; unsigned u; } c; c.h = h; return c.u;
}

// ---------------- epilogue: small terms, fp32, plain stores (runs FIRST) -----
__global__ __launch_bounds__(256) void epilogue_kernel(
    const float* __restrict__ x, const float* __restrict__ px,
    const float* __restrict__ noise,
    const float* __restrict__ hW, const float* __restrict__ hb,
    const float* __restrict__ pW, const float* __restrict__ pb,
    float* __restrict__ out)
{
    __shared__ float xs[4 * 512];
    __shared__ float pxs[4 * 512];
    __shared__ float ns[4 * 128];
    const int t  = threadIdx.x;
    const int og = blockIdx.x & 1;        // o half (0..1)
    const int bg = blockIdx.x >> 1;       // b group (0..127), 4 b's each
    const int b0 = bg * 4;

    for (int idx = t; idx < 2048; idx += 256) {
        int bb = idx >> 9, c = idx & 511;
        xs[idx]  = x [(b0 + bb) * 512 + c];
        pxs[idx] = px[(b0 + bb) * 512 + c];
    }
    for (int idx = t; idx < 512; idx += 256)
        ns[idx] = noise[(b0 + (idx >> 7)) * 128 + (idx & 127)];
    __syncthreads();

    const int o = og * 256 + t;
    float a0 = 0.f, a1 = 0.f, a2 = 0.f, a3 = 0.f;
    for (int i = 0; i < 512; ++i) {
        float hbv = hb[i * 512 + o];
        float pbv = pb[i * 512 + o];
        a0 += xs[0*512+i]*hbv + pxs[0*512+i]*pbv;
        a1 += xs[1*512+i]*hbv + pxs[1*512+i]*pbv;
        a2 += xs[2*512+i]*hbv + pxs[2*512+i]*pbv;
        a3 += xs[3*512+i]*hbv + pxs[3*512+i]*pbv;
    }
    const long base2 = (long)(MAIN_D + o) * 128;
    for (int n = 0; n < 128; ++n) {
        float w = hW[base2 + n] + pW[base2 + n];   // PRIOR_SCALE=1
        a0 += ns[0*128+n]*w;  a1 += ns[1*128+n]*w;
        a2 += ns[2*128+n]*w;  a3 += ns[3*128+n]*w;
    }
    const float tail = hb[MAIN_D + o] + pb[MAIN_D + o];
    out[(b0+0)*512 + o] = a0 + tail;
    out[(b0+1)*512 + o] = a1 + tail;
    out[(b0+2)*512 + o] = a2 + tail;
    out[(b0+3)*512 + o] = a3 + tail;
}

// ---------------- main bilinear GEMM: f16 MFMA, split-K, atomicAdd ----------
// grid (4 b-tiles, 4 o-tiles, 32 K-chunks); block 256 = 4 waves (2x2 of 64x64)
// K-chunk = 4096 = 32 i-values x 128 n; BK step = 32 (one i, one n-quarter).
__global__ __launch_bounds__(256) void main_gemm(
    const float* __restrict__ x, const float* __restrict__ px,
    const float* __restrict__ noise,
    const float* __restrict__ hW, const float* __restrict__ pW,
    float* __restrict__ out)
{
    __shared__ __attribute__((aligned(16))) _Float16 Al[128 * 40]; // A tile [b][k], stride 40
    __shared__ __attribute__((aligned(16))) _Float16 Bl[128 * 40]; // B tile [o][k], stride 40
    __shared__ __attribute__((aligned(16))) _Float16 nzl[128 * 130]; // noise [b][n] half
    __shared__ float xl[128 * 33];                                  // x tile [b][ii] fp32

    const int t  = threadIdx.x;
    const int b0 = blockIdx.x * 128;
    const int o0 = blockIdx.y * 128;
    const int bz = blockIdx.z;           // 0..31
    const int branch = bz >> 4;
    const int ic0 = (bz & 15) * 32;      // i range [ic0, ic0+32)
    const float* __restrict__ xsrc = branch ? px : x;
    const float* __restrict__ Ws   = branch ? pW : hW;

    // ---- stage noise tile 128b x 128n -> half, row stride 130 ----
    for (int idx = t; idx < 128 * 32; idx += 256) {
        int bb = idx >> 5, c = (idx & 31) * 4;
        const float4 v = *(const float4*)(noise + (b0 + bb) * 128 + c);
        __half2 h01 = __float22half2_rn(make_float2(v.x, v.y));
        __half2 h23 = __float22half2_rn(make_float2(v.z, v.w));
        *(__half2*)&nzl[bb * 130 + c]     = h01;
        *(__half2*)&nzl[bb * 130 + c + 2] = h23;
    }
    // ---- stage x tile 128b x 32i fp32, row stride 33 ----
    for (int idx = t; idx < 128 * 8; idx += 256) {
        int bb = idx >> 3, c = (idx & 7) * 4;
        const float4 v = *(const float4*)(xsrc + (b0 + bb) * 512 + ic0 + c);
        xl[bb*33 + c] = v.x; xl[bb*33 + c+1] = v.y;
        xl[bb*33 + c+2] = v.z; xl[bb*33 + c+3] = v.w;
    }
    __syncthreads();

    const int lane = t & 63;
    const int wm64 = ((t >> 6) >> 1) * 64;   // wave m offset
    const int wn64 = ((t >> 6) & 1) * 64;    // wave n offset
    const int quad = lane >> 4;
    const int l16  = lane & 15;
    const int oo = t & 127;                   // staging row (o for B, b for A)
    const int hf = t >> 7;                    // which 16-k half

    floatx4 acc[4][4];
#pragma unroll
    for (int a = 0; a < 4; ++a)
#pragma unroll
        for (int b = 0; b < 4; ++b) acc[a][b] = (floatx4)0.0f;

    // pipeline registers: W fp32 (next step) + A products as packed half2 x8
    float4 wr0, wr1, wr2, wr3;
    unsigned ap[8];

    // prologue: load step 0
    {
        const float* wp = Ws + ((long)(ic0 * 512 + o0 + oo)) * 128 + hf * 16;
        wr0 = *(const float4*)(wp);     wr1 = *(const float4*)(wp + 4);
        wr2 = *(const float4*)(wp + 8); wr3 = *(const float4*)(wp + 12);
        const float xv = xl[oo * 33];
        const _Float16* nrow = &nzl[oo * 130 + hf * 16];
#pragma unroll
        for (int k = 0; k < 8; ++k) {
            float2 f = __half22float2(*(const __half2*)(nrow + 2 * k));
            ap[k] = h2u(__float22half2_rn(make_float2(f.x * xv, f.y * xv)));
        }
    }

    for (int s = 0; s < 128; ++s) {
        __syncthreads();                     // prior MFMA frag reads done
        // store staged regs -> LDS
        {
            __half2 c0 = __float22half2_rn(make_float2(wr0.x, wr0.y));
            __half2 c1 = __float22half2_rn(make_float2(wr0.z, wr0.w));
            __half2 c2 = __float22half2_rn(make_float2(wr1.x, wr1.y));
            __half2 c3 = __float22half2_rn(make_float2(wr1.z, wr1.w));
            __half2 c4 = __float22half2_rn(make_float2(wr2.x, wr2.y));
            __half2 c5 = __float22half2_rn(make_float2(wr2.z, wr2.w));
            __half2 c6 = __float22half2_rn(make_float2(wr3.x, wr3.y));
            __half2 c7 = __float22half2_rn(make_float2(wr3.z, wr3.w));
            *(uint4*)&Bl[oo * 40 + hf * 16]     = make_uint4(h2u(c0), h2u(c1), h2u(c2), h2u(c3));
            *(uint4*)&Bl[oo * 40 + hf * 16 + 8] = make_uint4(h2u(c4), h2u(c5), h2u(c6), h2u(c7));
            *(uint4*)&Al[oo * 40 + hf * 16]     = make_uint4(ap[0], ap[1], ap[2], ap[3]);
            *(uint4*)&Al[oo * 40 + hf * 16 + 8] = make_uint4(ap[4], ap[5], ap[6], ap[7]);
        }
        __syncthreads();                     // tiles visible
        if (s + 1 < 128) {                   // prefetch next step (overlaps MFMA)
            const int s1 = s + 1;
            const int i  = ic0 + (s1 >> 2);
            const int n0 = (s1 & 3) << 5;
            const float* wp = Ws + ((long)(i * 512 + o0 + oo)) * 128 + n0 + hf * 16;
            wr0 = *(const float4*)(wp);     wr1 = *(const float4*)(wp + 4);
            wr2 = *(const float4*)(wp + 8); wr3 = *(const float4*)(wp + 12);
            const float xv = xl[oo * 33 + (s1 >> 2)];
            const _Float16* nrow = &nzl[oo * 130 + n0 + hf * 16];
#pragma unroll
            for (int k = 0; k < 8; ++k) {
                float2 f = __half22float2(*(const __half2*)(nrow + 2 * k));
                ap[k] = h2u(__float22half2_rn(make_float2(f.x * xv, f.y * xv)));
            }
        }
        // fragments + MFMA for step s
        half8 af[4], bf[4];
#pragma unroll
        for (int mf = 0; mf < 4; ++mf)
            af[mf] = *(half8*)&Al[(wm64 + mf * 16 + l16) * 40 + quad * 8];
#pragma unroll
        for (int nf = 0; nf < 4; ++nf)
            bf[nf] = *(half8*)&Bl[(wn64 + nf * 16 + l16) * 40 + quad * 8];
#pragma unroll
        for (int mf = 0; mf < 4; ++mf)
#pragma unroll
            for (int nf = 0; nf < 4; ++nf)
                acc[mf][nf] = __builtin_amdgcn_mfma_f32_16x16x32_f16(
                    af[mf], bf[nf], acc[mf][nf], 0, 0, 0);
    }

    // split-K accumulate: C/D layout row=(quad*4+r), col=l16 (verified m89/m91)
#pragma unroll
    for (int mf = 0; mf < 4; ++mf)
#pragma unroll
        for (int nf = 0; nf < 4; ++nf)
#pragma unroll
            for (int r = 0; r < 4; ++r) {
                int row = b0 + wm64 + mf * 16 + quad * 4 + r;
                int col = o0 + wn64 + nf * 16 + l16;
                atomicAdd(out + row * 512 + col, acc[mf][nf][r]);
            }
}

extern "C" void kernel_launch(void* const* d_in, const int* in_sizes, int n_in,
                              void* d_out, int out_size, void* d_ws, size_t ws_size,
                              hipStream_t stream) {
    const float* x  = (const float*)d_in[0];
    const float* px = (const float*)d_in[1];
    const float* nz = (const float*)d_in[2];
    const float* hW = (const float*)d_in[3];
    const float* hb = (const float*)d_in[4];
    const float* pW = (const float*)d_in[5];
    const float* pb = (const float*)d_in[6];
    float* out = (float*)d_out;

    // epilogue writes full small-term value with plain stores (no memset needed),
    // then main GEMM accumulates the bilinear terms atomically. Same stream => ordered.
    hipLaunchKernelGGL(epilogue_kernel, dim3(256), dim3(256), 0, stream,
                       x, px, nz, hW, hb, pW, pb, out);
    hipLaunchKernelGGL(main_gemm, dim3(4, 4, 32), dim3(256), 0, stream,
                       x, px, nz, hW, pW, out);
}

// Round 2
// 396.781 us; speedup vs baseline: 1.5887x; 1.5887x over previous
//
#include <hip/hip_runtime.h>
#include <hip/hip_fp16.h>

// out[b,o] = sum_{i,n} x[b,i]*noise[b,n]*hW[i*512+o,n]      (main, branch 0, z=0..15)
//          + sum_{i,n} px[b,i]*noise[b,n]*pW[i*512+o,n]     (main, branch 1, z=16..31)
//          + sum_i x[b,i]*hb[i*512+o] (+ prior)             (E1: extra K=32 step per chunk)
//          + sum_n noise[b,n]*(hW[MAIN_D+o,n]+pW[...])      (E2: extra macro on z%16==0)
//          + hb[MAIN_D+o] + pb[MAIN_D+o]                    (init kernel)
// PRIOR_SCALE = 1.0 folded. Main kernel accumulates via atomicAdd (split-K=32).

#define MAIN_D (512*512)

typedef _Float16 half8 __attribute__((ext_vector_type(8)));
typedef float floatx4 __attribute__((ext_vector_type(4)));

static __device__ __forceinline__ unsigned pk2(float a, float b) {
    union { __half2 h; unsigned u; } c;
    c.h = __float22half2_rn(make_float2(a, b));
    return c.u;
}

// ---- init: out[b,o] = hb[MAIN_D+o] + pb[MAIN_D+o] (plain stores, runs first) ----
__global__ __launch_bounds__(256) void init_kernel(
    const float* __restrict__ hb, const float* __restrict__ pb,
    float* __restrict__ out)
{
    const int idx = blockIdx.x * 256 + threadIdx.x;   // 65536 threads x float4
    const int o4 = (idx * 4) & 511;
    float4 v;
    v.x = hb[MAIN_D + o4 + 0] + pb[MAIN_D + o4 + 0];
    v.y = hb[MAIN_D + o4 + 1] + pb[MAIN_D + o4 + 1];
    v.z = hb[MAIN_D + o4 + 2] + pb[MAIN_D + o4 + 2];
    v.w = hb[MAIN_D + o4 + 3] + pb[MAIN_D + o4 + 3];
    *(float4*)(out + idx * 4) = v;
}

// ---- main: f16 MFMA, macro-steps over i (contiguous 64KB W slab per macro) ----
// grid (4 b-tiles, 4 o-tiles, 32 = branch*16 + i-chunk); block 256 = 4 waves (2x2)
__global__ __launch_bounds__(256, 2) void main_gemm(
    const float* __restrict__ x, const float* __restrict__ px,
    const float* __restrict__ noise,
    const float* __restrict__ hW, const float* __restrict__ hb,
    const float* __restrict__ pW, const float* __restrict__ pb,
    float* __restrict__ out)
{
    // B4l: 4 quarter-tiles [q][128 o][40 halfs] (cols 0..31 used). 40960 B.
    // Also reused (before main loop) as noise staging [128][136] = 34816 B.
    __shared__ __attribute__((aligned(16))) _Float16 B4l[4 * 128 * 40];
    __shared__ __attribute__((aligned(16))) _Float16 xhl[128 * 40];   // x tile [b][i] half

    const int t  = threadIdx.x;
    const int b0 = blockIdx.x * 128;
    const int o0 = blockIdx.y * 128;
    const int bz = blockIdx.z;
    const int branch = bz >> 4;
    const int ic0 = (bz & 15) * 32;
    const float* __restrict__ xsrc = branch ? px : x;
    const float* __restrict__ Ws   = branch ? pW : hW;
    const float* __restrict__ bias = branch ? pb : hb;
    const bool doE2 = ((bz & 15) == 0);
    const int nmacro = doE2 ? 33 : 32;

    // ---- stage x tile 128b x 32i -> half, stride 40 ----
    for (int idx = t; idx < 128 * 8; idx += 256) {
        int bb = idx >> 3, c = (idx & 7) * 4;
        float4 v = *(const float4*)(xsrc + (b0 + bb) * 512 + ic0 + c);
        *(unsigned*)&xhl[bb * 40 + c]     = pk2(v.x, v.y);
        *(unsigned*)&xhl[bb * 40 + c + 2] = pk2(v.z, v.w);
    }
    // ---- stage noise 128b x 128n -> half into B4l area, stride 136 (16B-mult) ----
    _Float16* nzl = B4l;
    for (int idx = t; idx < 128 * 32; idx += 256) {
        int bb = idx >> 5, c = (idx & 31) * 4;
        float4 v = *(const float4*)(noise + (b0 + bb) * 128 + c);
        *(unsigned*)&nzl[bb * 136 + c]     = pk2(v.x, v.y);
        *(unsigned*)&nzl[bb * 136 + c + 2] = pk2(v.z, v.w);
    }
    __syncthreads();

    const int lane = t & 63;
    const int wm64 = ((t >> 6) >> 1) * 64;
    const int wn64 = ((t >> 6) & 1) * 64;
    const int quad = lane >> 4;
    const int l16  = lane & 15;

    // noise A-fragments in registers: nzf[mf][q][j] = nz_h[row_mf][q*32+quad*8+j]
    half8 nzf[4][4];
#pragma unroll
    for (int mf = 0; mf < 4; ++mf)
#pragma unroll
        for (int q = 0; q < 4; ++q)
            nzf[mf][q] = *(half8*)&nzl[(wm64 + mf * 16 + l16) * 136 + q * 32 + quad * 8];

    floatx4 acc[4][4];
#pragma unroll
    for (int a = 0; a < 4; ++a)
#pragma unroll
        for (int b = 0; b < 4; ++b) acc[a][b] = (floatx4)0.0f;

    // W slab staging: flat-coalesced. float4 index f = j*256 + t over 64KB slab.
    // thread t: col window c4 = (4t)&127 (single quarter q = (t>>3)&3), rows j*8+(t>>5).
    const int sq   = (t >> 3) & 3;        // quarter
    const int sc   = (4 * t) & 31;        // col within quarter
    const int srh  = t >> 5;              // row sub-offset
    float4 wr[16];
    {
        const float* p = Ws + (long)(ic0 * 512 + o0) * 128;
#pragma unroll
        for (int j = 0; j < 16; ++j)
            wr[j] = *(const float4*)(p + (j * 256 + t) * 4);
    }

    for (int m = 0; m < nmacro; ++m) {
        __syncthreads();                      // prior frag reads done (incl. nzf prologue)
        // write staged regs -> B4l quarter sq, rows j*8+srh, cols sc..sc+4
#pragma unroll
        for (int j = 0; j < 16; ++j) {
            _Float16* dst = &B4l[sq * 5120 + (j * 8 + srh) * 40 + sc];
            *(uint2*)dst = make_uint2(pk2(wr[j].x, wr[j].y), pk2(wr[j].z, wr[j].w));
        }
        __syncthreads();                      // tile visible
        if (m + 1 < nmacro) {                 // prefetch next slab (overlaps MFMA)
            long rowbase = (m + 1 < 32) ? (long)((ic0 + m + 1) * 512 + o0)
                                        : (long)(MAIN_D + o0);
            const float* p = Ws + rowbase * 128;
#pragma unroll
            for (int j = 0; j < 16; ++j)
                wr[j] = *(const float4*)(p + (j * 256 + t) * 4);
        }
        const bool isE2 = (m >= 32);
        half8 xv[4];
        if (!isE2) {
#pragma unroll
            for (int mf = 0; mf < 4; ++mf) {
                _Float16 xs = xhl[(wm64 + mf * 16 + l16) * 40 + m];
#pragma unroll
                for (int j = 0; j < 8; ++j) xv[mf][j] = xs;
            }
        }
#pragma unroll
        for (int q = 0; q < 4; ++q) {
            half8 bfr[4], afr[4];
#pragma unroll
            for (int nf = 0; nf < 4; ++nf)
                bfr[nf] = *(half8*)&B4l[q * 5120 + (wn64 + nf * 16 + l16) * 40 + quad * 8];
#pragma unroll
            for (int mf = 0; mf < 4; ++mf)
                afr[mf] = isE2 ? nzf[mf][q] : (half8)(nzf[mf][q] * xv[mf]);
#pragma unroll
            for (int mf = 0; mf < 4; ++mf)
#pragma unroll
                for (int nf = 0; nf < 4; ++nf)
                    acc[mf][nf] = __builtin_amdgcn_mfma_f32_16x16x32_f16(
                        afr[mf], bfr[nf], acc[mf][nf], 0, 0, 0);
        }
    }

    // ---- E1: bias GEMM step, K=32 (A = x tile already in LDS) ----
    __syncthreads();
    {
        const int oo = t >> 1, kh = (t & 1) * 16;
        float tmp[16];
#pragma unroll
        for (int j = 0; j < 16; ++j)
            tmp[j] = bias[(long)(ic0 + kh + j) * 512 + o0 + oo];
        _Float16* dst = &B4l[oo * 40 + kh];
        *(uint4*)(dst)     = make_uint4(pk2(tmp[0], tmp[1]),  pk2(tmp[2], tmp[3]),
                                        pk2(tmp[4], tmp[5]),  pk2(tmp[6], tmp[7]));
        *(uint4*)(dst + 8) = make_uint4(pk2(tmp[8], tmp[9]),  pk2(tmp[10], tmp[11]),
                                        pk2(tmp[12], tmp[13]), pk2(tmp[14], tmp[15]));
    }
    __syncthreads();
    {
        half8 afr[4], bfr[4];
#pragma unroll
        for (int mf = 0; mf < 4; ++mf)
            afr[mf] = *(half8*)&xhl[(wm64 + mf * 16 + l16) * 40 + quad * 8];
#pragma unroll
        for (int nf = 0; nf < 4; ++nf)
            bfr[nf] = *(half8*)&B4l[(wn64 + nf * 16 + l16) * 40 + quad * 8];
#pragma unroll
        for (int mf = 0; mf < 4; ++mf)
#pragma unroll
            for (int nf = 0; nf < 4; ++nf)
                acc[mf][nf] = __builtin_amdgcn_mfma_f32_16x16x32_f16(
                    afr[mf], bfr[nf], acc[mf][nf], 0, 0, 0);
    }

    // ---- split-K accumulate (v1-verified C/D mapping) ----
#pragma unroll
    for (int mf = 0; mf < 4; ++mf)
#pragma unroll
        for (int nf = 0; nf < 4; ++nf)
#pragma unroll
            for (int r = 0; r < 4; ++r) {
                int row = b0 + wm64 + mf * 16 + quad * 4 + r;
                int col = o0 + wn64 + nf * 16 + l16;
                atomicAdd(out + row * 512 + col, acc[mf][nf][r]);
            }
}

extern "C" void kernel_launch(void* const* d_in, const int* in_sizes, int n_in,
                              void* d_out, int out_size, void* d_ws, size_t ws_size,
                              hipStream_t stream) {
    const float* x  = (const float*)d_in[0];
    const float* px = (const float*)d_in[1];
    const float* nz = (const float*)d_in[2];
    const float* hW = (const float*)d_in[3];
    const float* hb = (const float*)d_in[4];
    const float* pW = (const float*)d_in[5];
    const float* pb = (const float*)d_in[6];
    float* out = (float*)d_out;

    hipLaunchKernelGGL(init_kernel, dim3(256), dim3(256), 0, stream, hb, pb, out);
    hipLaunchKernelGGL(main_gemm, dim3(4, 4, 32), dim3(256), 0, stream,
                       x, px, nz, hW, hb, pW, pb, out);
}

// Round 3
// 319.321 us; speedup vs baseline: 1.9741x; 1.2426x over previous
//
#include <hip/hip_runtime.h>
#include <hip/hip_fp16.h>

// out[b,o] = sum_{i,n} x[b,i]*noise[b,n]*hW[i*512+o,n]      (main, branch 0, z=0..15)
//          + sum_{i,n} px[b,i]*noise[b,n]*pW[i*512+o,n]     (main, branch 1, z=16..31)
//          + sum_i x[b,i]*hb[i*512+o] (+ prior)             (E1: extra K=32 MFMA after loop)
//          + sum_n noise[b,n]*(hW[MAIN_D+o,n]+pW[...,n])    (E2: macro 33 on z%16==0)
//          + hb[MAIN_D+o] + pb[MAIN_D+o]                    (init kernel)
// M-tile 256 (halves logical W traffic vs R2), dbuf W tile, 1 barrier/macro.

#define MAIN_D (512*512)

typedef _Float16 half8 __attribute__((ext_vector_type(8)));
typedef float floatx4 __attribute__((ext_vector_type(4)));

static __device__ __forceinline__ unsigned pk2(float a, float b) {
    union { __half2 h; unsigned u; } c;
    c.h = __float22half2_rn(make_float2(a, b));
    return c.u;
}

// ---- init: out[b,o] = hb[MAIN_D+o] + pb[MAIN_D+o] ----
__global__ __launch_bounds__(256) void init_kernel(
    const float* __restrict__ hb, const float* __restrict__ pb,
    float* __restrict__ out)
{
    const int idx = blockIdx.x * 256 + threadIdx.x;   // 65536 threads x float4
    const int o4 = (idx * 4) & 511;
    float4 v;
    v.x = hb[MAIN_D + o4 + 0] + pb[MAIN_D + o4 + 0];
    v.y = hb[MAIN_D + o4 + 1] + pb[MAIN_D + o4 + 1];
    v.z = hb[MAIN_D + o4 + 2] + pb[MAIN_D + o4 + 2];
    v.w = hb[MAIN_D + o4 + 3] + pb[MAIN_D + o4 + 3];
    *(float4*)(out + idx * 4) = v;
}

// ---- main: 256 blocks x 512 threads (8 waves, 4m x 2n of 64x64 tiles) ----
__global__ __launch_bounds__(512, 2) void main_gemm(
    const float* __restrict__ x, const float* __restrict__ px,
    const float* __restrict__ noise,
    const float* __restrict__ hW, const float* __restrict__ hb,
    const float* __restrict__ pW, const float* __restrict__ pb,
    float* __restrict__ out)
{
    // W tile double buffer [2][128 o][136 halfs] (cols 0..127 = n). 69632 B.
    // Prologue overlay: noise staging [256 b][136 halfs].
    __shared__ __attribute__((aligned(16))) _Float16 Bl[2][128 * 136];
    __shared__ __attribute__((aligned(16))) _Float16 xhl[256 * 40];  // x [b][i] half

    const int t = threadIdx.x;
    // sibling-swizzled decode: the 2 blocks sharing a W slab are 8 apart in
    // linear index (same XCD under round-robin dispatch) -> L2 slab sharing.
    const int lin  = blockIdx.x;            // 0..255
    const int s    = (lin >> 3) & 1;        // b-tile (sibling id)
    const int g    = ((lin >> 4) << 3) | (lin & 7);   // 0..127 slab group
    const int z    = g >> 2;                // 0..31: branch*16 + i-chunk
    const int y    = g & 3;                 // o-tile
    const int b0   = s * 256;
    const int o0   = y * 128;
    const int branch = z >> 4;
    const int ic0  = (z & 15) * 32;
    const float* __restrict__ xsrc = branch ? px : x;
    const float* __restrict__ Ws   = branch ? pW : hW;
    const float* __restrict__ bias = branch ? pb : hb;
    const int nmacro = ((z & 15) == 0) ? 33 : 32;

    // ---- stage x tile 256b x 32i -> half, stride 40 ----
#pragma unroll
    for (int k = 0; k < 4; ++k) {
        int idx = k * 512 + t;              // 0..2047
        int bb = idx >> 3, c = (idx & 7) * 4;
        float4 v = *(const float4*)(xsrc + (b0 + bb) * 512 + ic0 + c);
        *(unsigned*)&xhl[bb * 40 + c]     = pk2(v.x, v.y);
        *(unsigned*)&xhl[bb * 40 + c + 2] = pk2(v.z, v.w);
    }
    // ---- stage noise 256b x 128n -> half into Bl overlay, stride 136 ----
    _Float16* nzl = &Bl[0][0];
#pragma unroll
    for (int k = 0; k < 16; ++k) {
        int idx = k * 512 + t;              // 0..8191
        int bb = idx >> 5, c = (idx & 31) * 4;
        float4 v = *(const float4*)(noise + (b0 + bb) * 128 + c);
        *(unsigned*)&nzl[bb * 136 + c]     = pk2(v.x, v.y);
        *(unsigned*)&nzl[bb * 136 + c + 2] = pk2(v.z, v.w);
    }
    __syncthreads();

    const int lane = t & 63;
    const int w    = t >> 6;
    const int wm64 = (w >> 1) * 64;         // 0,64,128,192
    const int wn64 = (w & 1) * 64;          // 0,64
    const int quad = lane >> 4;
    const int l16  = lane & 15;

    // noise A-fragments in registers: nzf[mf][q][j] = nz_h[row][q*32+quad*8+j]
    half8 nzf[4][4];
#pragma unroll
    for (int mf = 0; mf < 4; ++mf)
#pragma unroll
        for (int q = 0; q < 4; ++q)
            nzf[mf][q] = *(half8*)&nzl[(wm64 + mf * 16 + l16) * 136 + q * 32 + quad * 8];

    floatx4 acc[4][4];
#pragma unroll
    for (int a = 0; a < 4; ++a)
#pragma unroll
        for (int b = 0; b < 4; ++b) acc[a][b] = (floatx4)0.0f;

    // W slab staging: 64KB slab = 128 rows x 128 floats; thread handles 4 chunks
    // of 8 contiguous floats -> one 16B LDS write each (conflict-free minimum).
    float4 wa[4], wb[4];
    {
        const float* p = Ws + (long)(ic0 * 512 + o0) * 128;
#pragma unroll
        for (int j = 0; j < 4; ++j) {
            int c = j * 512 + t;
            int off = (c >> 4) * 128 + (c & 15) * 8;
            wa[j] = *(const float4*)(p + off);
            wb[j] = *(const float4*)(p + off + 4);
        }
    }
    __syncthreads();   // nzf overlay reads complete before first Bl write

    for (int m = 0; m < nmacro; ++m) {
        _Float16* buf = &Bl[m & 1][0];
        // write staged regs -> current buffer (ds_write_b128, lane-consecutive)
#pragma unroll
        for (int j = 0; j < 4; ++j) {
            int c = j * 512 + t;
            int row = c >> 4, col8 = (c & 15) * 8;
            *(uint4*)&buf[row * 136 + col8] = make_uint4(
                pk2(wa[j].x, wa[j].y), pk2(wa[j].z, wa[j].w),
                pk2(wb[j].x, wb[j].y), pk2(wb[j].z, wb[j].w));
        }
        __syncthreads();                     // one barrier per macro (dbuf)
        if (m + 1 < nmacro) {                // prefetch next slab (in flight over MFMA)
            long rb = (m + 1 < 32) ? (long)((ic0 + m + 1) * 512 + o0)
                                   : (long)(MAIN_D + o0);
            const float* p = Ws + rb * 128;
#pragma unroll
            for (int j = 0; j < 4; ++j) {
                int c = j * 512 + t;
                int off = (c >> 4) * 128 + (c & 15) * 8;
                wa[j] = *(const float4*)(p + off);
                wb[j] = *(const float4*)(p + off + 4);
            }
        }
        const bool isE2 = (m >= 32);
        _Float16 xs[4];
        if (!isE2) {
#pragma unroll
            for (int mf = 0; mf < 4; ++mf)
                xs[mf] = xhl[(wm64 + mf * 16 + l16) * 40 + m];
        }
#pragma unroll
        for (int q = 0; q < 4; ++q) {
            half8 bfr[4], afr[4];
#pragma unroll
            for (int nf = 0; nf < 4; ++nf)
                bfr[nf] = *(half8*)&buf[(wn64 + nf * 16 + l16) * 136 + q * 32 + quad * 8];
#pragma unroll
            for (int mf = 0; mf < 4; ++mf) {
                if (isE2) afr[mf] = nzf[mf][q];
                else {
                    half8 xv;
#pragma unroll
                    for (int j = 0; j < 8; ++j) xv[j] = xs[mf];
                    afr[mf] = nzf[mf][q] * xv;
                }
            }
#pragma unroll
            for (int mf = 0; mf < 4; ++mf)
#pragma unroll
                for (int nf = 0; nf < 4; ++nf)
                    acc[mf][nf] = __builtin_amdgcn_mfma_f32_16x16x32_f16(
                        afr[mf], bfr[nf], acc[mf][nf], 0, 0, 0);
        }
    }

    // ---- E1: bias GEMM step, K=32 (A = x tile in LDS) ----
    __syncthreads();
    {
        const int oo = t >> 2, kh = (t & 3) * 8;
        float tmp[8];
#pragma unroll
        for (int j = 0; j < 8; ++j)
            tmp[j] = bias[(long)(ic0 + kh + j) * 512 + o0 + oo];
        *(uint4*)&Bl[0][oo * 136 + kh] = make_uint4(
            pk2(tmp[0], tmp[1]), pk2(tmp[2], tmp[3]),
            pk2(tmp[4], tmp[5]), pk2(tmp[6], tmp[7]));
    }
    __syncthreads();
    {
        half8 afr[4], bfr[4];
#pragma unroll
        for (int mf = 0; mf < 4; ++mf)
            afr[mf] = *(half8*)&xhl[(wm64 + mf * 16 + l16) * 40 + quad * 8];
#pragma unroll
        for (int nf = 0; nf < 4; ++nf)
            bfr[nf] = *(half8*)&Bl[0][(wn64 + nf * 16 + l16) * 136 + quad * 8];
#pragma unroll
        for (int mf = 0; mf < 4; ++mf)
#pragma unroll
            for (int nf = 0; nf < 4; ++nf)
                acc[mf][nf] = __builtin_amdgcn_mfma_f32_16x16x32_f16(
                    afr[mf], bfr[nf], acc[mf][nf], 0, 0, 0);
    }

    // ---- split-K accumulate (C/D: row=quad*4+r, col=l16; verified R1/R2) ----
#pragma unroll
    for (int mf = 0; mf < 4; ++mf)
#pragma unroll
        for (int nf = 0; nf < 4; ++nf)
#pragma unroll
            for (int r = 0; r < 4; ++r) {
                int row = b0 + wm64 + mf * 16 + quad * 4 + r;
                int col = o0 + wn64 + nf * 16 + l16;
                atomicAdd(out + row * 512 + col, acc[mf][nf][r]);
            }
}

extern "C" void kernel_launch(void* const* d_in, const int* in_sizes, int n_in,
                              void* d_out, int out_size, void* d_ws, size_t ws_size,
                              hipStream_t stream) {
    const float* x  = (const float*)d_in[0];
    const float* px = (const float*)d_in[1];
    const float* nz = (const float*)d_in[2];
    const float* hW = (const float*)d_in[3];
    const float* hb = (const float*)d_in[4];
    const float* pW = (const float*)d_in[5];
    const float* pb = (const float*)d_in[6];
    float* out = (float*)d_out;

    hipLaunchKernelGGL(init_kernel, dim3(256), dim3(256), 0, stream, hb, pb, out);
    hipLaunchKernelGGL(main_gemm, dim3(256), dim3(512), 0, stream,
                       x, px, nz, hW, hb, pW, pb, out);
}